// Round 14
// baseline (130.990 us; speedup 1.0000x reference)
//
#include <hip/hip_runtime.h>

// Fixed problem geometry: D=64, n_gt=512, npg=399 nodes/tree, 398 edges/tree.
#define SMAX 200
#define NPG 399

typedef __bf16 bf16x8 __attribute__((ext_vector_type(8)));
typedef _Float16 half8 __attribute__((ext_vector_type(8)));
typedef float f32x4 __attribute__((ext_vector_type(4)));

__device__ __forceinline__ unsigned short f2bf(float f) {
  unsigned u = __float_as_uint(f);
  unsigned r = (u + 0x7FFFu + ((u >> 16) & 1u)) >> 16;
  return (unsigned short)r;
}
// x rows live in LDS as 8 chunks of 8 f16; chunk slot = chunk ^ (node&7).
__device__ __forceinline__ int xel(int node, int dim) {
  return node * 64 + ((((dim >> 3)) ^ (node & 7)) << 3) + (dim & 7);
}

// Build A-operand fragments (mf as bf16, pre-swizzled into the 16x16x32 MFMA
// lane layout) and packed mf bitmasks.
__global__ __launch_bounds__(256) void k_prep(const int* __restrict__ clade,
                                              unsigned short* __restrict__ mfA,
                                              unsigned* __restrict__ mfbits,
                                              int n_edges, int n_species) {
  int stride = gridDim.x * 256;
  for (int idx = blockIdx.x * 256 + threadIdx.x; idx < 25 * 7 * 512;
       idx += stride) {
    int fi = idx >> 9, within = idx & 511;
    int mt = fi / 7, kt = fi % 7;
    int l = within >> 3, j = within & 7;
    int e = mt * 16 + (l & 15);
    int s = kt * 32 + ((l >> 4) & 3) * 8 + j;
    unsigned short v = 0;
    if (e < n_edges && s < n_species && clade[(size_t)e * n_species + s] != 0)
      v = 0x3F80;  // bf16(1.0)
    mfA[idx] = v;
  }
  for (int idx = blockIdx.x * 256 + threadIdx.x; idx < 400 * 8; idx += stride) {
    int e = idx >> 3, w = idx & 7;
    unsigned bits = 0;
    if (e < n_edges && w < 7) {
      for (int b = 0; b < 32; ++b) {
        int s = w * 32 + b;
        if (s < n_species && clade[(size_t)e * n_species + s] != 0)
          bits |= 1u << b;
      }
    }
    mfbits[idx] = bits;
  }
}

// Mega-kernel v5: one block per gene tree, 12 waves (768 thr) = 3 waves/SIMD.
// Per-layer weight staging keeps LDS at 153.6 KB (1 WG/CU). Gather is the
// counted, unroll-pipelined lane-parallel loop producing the MFMA A-fragment
// in registers. Tail (pooling + clade MFMA) aliases dead sT/sWf regions.
__global__ __launch_bounds__(768) void k_tree(
    const float* __restrict__ emb, const int* __restrict__ sp,
    const int* __restrict__ leaf, const int* __restrict__ src,
    const int* __restrict__ dst, const float* __restrict__ W1,
    const float* __restrict__ b1, const float* __restrict__ W2,
    const float* __restrict__ b2, const float* __restrict__ eps_p,
    const float* __restrict__ gam, const float* __restrict__ bet,
    const unsigned short* __restrict__ mfA, const unsigned* __restrict__ mfbits,
    _Float16* __restrict__ gmat, float* __restrict__ has, int npg,
    int n_species, int n_edges, int n_gt) {
  __shared__ __attribute__((aligned(16))) _Float16 sA[NPG * 64];
  __shared__ __attribute__((aligned(16))) _Float16 sB[NPG * 64];
  __shared__ __attribute__((aligned(16))) _Float16 sWf[2][4096];
  __shared__ __attribute__((aligned(16))) _Float16 sT[14][1024];  // 12 used
  __shared__ int sStart[NPG + 1];
  __shared__ int sChild[NPG - 1];
  __shared__ int sPar[NPG];
  __shared__ int sCnt[NPG];

  int g = blockIdx.x, tid = threadIdx.x;
  int base = g * npg, nEt = npg - 1, ebase = g * nEt;
  int w = tid >> 6, lane = tid & 63;
  int cc = lane & 15, gq = lane >> 4;

  // ---- 0a: zero CSR counters
  for (int i = tid; i < npg + 1; i += 768) sStart[i] = 0;
  for (int i = tid; i < npg; i += 768) sCnt[i] = 0;
  __syncthreads();
  // ---- 0b: emb gather (swizzled chunks), edges + histogram
  for (int idx = tid; idx < npg * 8; idx += 768) {
    int node = idx >> 3, ch = idx & 7;
    int s = sp[base + node];
    int row = (s < 0) ? n_species : s;
    float4 v0 = reinterpret_cast<const float4*>(emb)[row * 16 + ch * 2];
    float4 v1 = reinterpret_cast<const float4*>(emb)[row * 16 + ch * 2 + 1];
    half8 h;
    h[0] = (_Float16)v0.x; h[1] = (_Float16)v0.y;
    h[2] = (_Float16)v0.z; h[3] = (_Float16)v0.w;
    h[4] = (_Float16)v1.x; h[5] = (_Float16)v1.y;
    h[6] = (_Float16)v1.z; h[7] = (_Float16)v1.w;
    *reinterpret_cast<half8*>(&sA[node * 64 + ((ch ^ (node & 7)) << 3)]) = h;
  }
  for (int i = tid; i < nEt; i += 768) {
    int c = src[ebase + i] - base;
    int p = dst[ebase + i] - base;
    sPar[c] = p;
    atomicAdd(&sStart[p + 1], 1);
  }
  __syncthreads();
  // ---- 0c: inclusive scan (wave 0, shfl)
  if (w == 0) {
    int run = 0;
    for (int chunk = 0; chunk * 64 < npg + 1; ++chunk) {
      int idx = chunk * 64 + lane;
      int v = (idx < npg + 1) ? sStart[idx] : 0;
      for (int off = 1; off < 64; off <<= 1) {
        int t2 = __shfl_up(v, off);
        if (lane >= off) v += t2;
      }
      v += run;
      if (idx < npg + 1) sStart[idx] = v;
      run = __shfl(v, 63);
    }
  }
  __syncthreads();
  // ---- 0d: scatter children
  for (int c = tid + 1; c < npg; c += 768) {
    int p = sPar[c];
    int pos = sStart[p] + atomicAdd(&sCnt[p], 1);
    sChild[pos] = c;
  }
  __syncthreads();

  // ---- layers
  _Float16* tb = sT[w];
  int t0w = (w * 25) / 12;
  int t1w = ((w + 1) * 25) / 12;
  for (int l = 0; l < 2; ++l) {
    // stage this layer's weights (frag-swizzled)
    for (int idx = tid; idx < 4096; idx += 768) {
      int k = idx >> 6, n = idx & 63;
      int frag = (k >> 5) * 4 + (n >> 4);
      int ln = ((k >> 3) & 3) * 16 + (n & 15);
      int j = k & 7;
      int o = frag * 512 + ln * 8 + j;
      sWf[0][o] = (_Float16)W1[l * 4096 + idx];
      sWf[1][o] = (_Float16)W2[l * 4096 + idx];
    }
    __syncthreads();
    const _Float16* xin = l ? sB : sA;
    _Float16* xout = l ? sA : sB;
    const half8* xin8 = reinterpret_cast<const half8*>(xin);
    float e1 = 1.0f + eps_p[l];
    float b1v[4], b2v[4], gv[4], bv[4];
#pragma unroll
    for (int nt = 0; nt < 4; ++nt) {
      b1v[nt] = b1[l * 64 + cc + 16 * nt];
      b2v[nt] = b2[l * 64 + cc + 16 * nt];
      gv[nt] = gam[l * 64 + cc + 16 * nt];
      bv[nt] = bet[l * 64 + cc + 16 * nt];
    }
    const half8* B1 = reinterpret_cast<const half8*>(sWf[0]);
    const half8* B2 = reinterpret_cast<const half8*>(sWf[1]);
    for (int t = t0w; t < t1w; ++t) {
      int n0 = t * 16;
      // lane-parallel msg gather; accumulator IS the A-fragment (f32)
      int node = n0 + cc;
      bool vn = node < npg;
      int nd2 = vn ? node : 0;
      int j0v = vn ? sStart[nd2] : 0;
      int cnt = vn ? (sStart[nd2 + 1] - j0v) : 0;
      half8 s0 = xin8[nd2 * 8 + (gq ^ (nd2 & 7))];
      half8 s1 = xin8[nd2 * 8 + ((4 + gq) ^ (nd2 & 7))];
      bool hasp = vn && node > 0;
      int pr = hasp ? sPar[nd2] : 0;
      half8 p0 = xin8[pr * 8 + (gq ^ (pr & 7))];
      half8 p1 = xin8[pr * 8 + ((4 + gq) ^ (pr & 7))];
      float a0f[8], a1f[8];
#pragma unroll
      for (int d = 0; d < 8; ++d) {
        a0f[d] = e1 * (float)s0[d] + (hasp ? (float)p0[d] : 0.f);
        a1f[d] = e1 * (float)s1[d] + (hasp ? (float)p1[d] : 0.f);
      }
      int cmax = cnt;
#pragma unroll
      for (int off = 1; off < 64; off <<= 1)
        cmax = max(cmax, __shfl_xor(cmax, off));
      cmax = __builtin_amdgcn_readfirstlane(cmax);
#pragma unroll 2
      for (int k = 0; k < cmax; ++k) {
        bool act = k < cnt;
        int jidx = act ? (j0v + k) : 0;
        int c = sChild[jidx];
        half8 v0 = xin8[c * 8 + (gq ^ (c & 7))];
        half8 v1 = xin8[c * 8 + ((4 + gq) ^ (c & 7))];
        if (act) {
#pragma unroll
          for (int d = 0; d < 8; ++d) {
            a0f[d] += (float)v0[d];
            a1f[d] += (float)v1[d];
          }
        }
      }
      half8 a0, a1;
#pragma unroll
      for (int d = 0; d < 8; ++d) {
        a0[d] = (_Float16)a0f[d];
        a1[d] = (_Float16)a1f[d];
      }
      // MFMA 1 + relu -> per-wave tile buffer (XOR-swizzled)
      f32x4 tacc[4];
#pragma unroll
      for (int nt = 0; nt < 4; ++nt) tacc[nt] = (f32x4){0.f, 0.f, 0.f, 0.f};
#pragma unroll
      for (int nt = 0; nt < 4; ++nt) {
        tacc[nt] = __builtin_amdgcn_mfma_f32_16x16x32_f16(
            a0, B1[nt * 64 + lane], tacc[nt], 0, 0, 0);
        tacc[nt] = __builtin_amdgcn_mfma_f32_16x16x32_f16(
            a1, B1[(4 + nt) * 64 + lane], tacc[nt], 0, 0, 0);
      }
#pragma unroll
      for (int nt = 0; nt < 4; ++nt)
#pragma unroll
        for (int r = 0; r < 4; ++r) {
          int m = gq * 4 + r;
          tb[m * 64 + ((cc + 16 * nt) ^ ((m & 7) << 3))] =
              (_Float16)fmaxf(tacc[nt][r] + b1v[nt], 0.f);
        }
      int sw = (cc & 7) << 3;
      half8 c0 =
          *reinterpret_cast<const half8*>(&tb[cc * 64 + ((gq * 8) ^ sw)]);
      half8 c1 =
          *reinterpret_cast<const half8*>(&tb[cc * 64 + ((32 + gq * 8) ^ sw)]);
      f32x4 hacc[4];
#pragma unroll
      for (int nt = 0; nt < 4; ++nt) hacc[nt] = (f32x4){0.f, 0.f, 0.f, 0.f};
#pragma unroll
      for (int nt = 0; nt < 4; ++nt) {
        hacc[nt] = __builtin_amdgcn_mfma_f32_16x16x32_f16(
            c0, B2[nt * 64 + lane], hacc[nt], 0, 0, 0);
        hacc[nt] = __builtin_amdgcn_mfma_f32_16x16x32_f16(
            c1, B2[(4 + nt) * 64 + lane], hacc[nt], 0, 0, 0);
      }
      // residual + LayerNorm (f32)
      float y[4][4];
#pragma unroll
      for (int r = 0; r < 4; ++r) {
        int nd3 = n0 + gq * 4 + r;
        bool v3 = nd3 < npg;
        int nds = v3 ? nd3 : 0;
#pragma unroll
        for (int nt = 0; nt < 4; ++nt) {
          float xv = (float)xin[xel(nds, cc + 16 * nt)];
          y[r][nt] = (v3 ? xv : 0.f) + hacc[nt][r] + b2v[nt];
        }
      }
#pragma unroll
      for (int r = 0; r < 4; ++r) {
        float s = y[r][0] + y[r][1] + y[r][2] + y[r][3];
        s += __shfl_xor(s, 1);
        s += __shfl_xor(s, 2);
        s += __shfl_xor(s, 4);
        s += __shfl_xor(s, 8);
        float mu = s * (1.f / 64.f);
        float d0 = y[r][0] - mu, d1 = y[r][1] - mu;
        float d2 = y[r][2] - mu, d3 = y[r][3] - mu;
        float v = d0 * d0 + d1 * d1 + d2 * d2 + d3 * d3;
        v += __shfl_xor(v, 1);
        v += __shfl_xor(v, 2);
        v += __shfl_xor(v, 4);
        v += __shfl_xor(v, 8);
        float iv = rsqrtf(v * (1.f / 64.f) + 1e-5f);
        int nd3 = n0 + gq * 4 + r;
        if (nd3 < npg) {
#pragma unroll
          for (int nt = 0; nt < 4; ++nt)
            xout[xel(nd3, cc + 16 * nt)] =
                (_Float16)((y[r][nt] - mu) * iv * gv[nt] + bv[nt]);
        }
      }
    }
    __syncthreads();
  }

  // ---- 3: species pooling (final x is in sA). Aliases: sBf on dead sT,
  //         aux on dead sWf.
  unsigned short* sBfU = reinterpret_cast<unsigned short*>(&sT[0][0]);
  char* aux = reinterpret_cast<char*>(&sWf[0][0]);
  float* sInv = reinterpret_cast<float*>(aux);
  float* sHas = reinterpret_cast<float*>(aux + 1600);
  unsigned* svb = reinterpret_cast<unsigned*>(aux + 3200);
  for (int i = tid; i < n_species + 1; i += 768) sStart[i] = 0;
  for (int i = tid; i < n_species; i += 768) sCnt[i] = 0;
  {
    float4 z4 = {0.f, 0.f, 0.f, 0.f};
    for (int i = tid; i < 1792; i += 768)
      reinterpret_cast<float4*>(sBfU)[i] = z4;
  }
  __syncthreads();
  for (int i = tid; i < npg; i += 768) {
    int s = sp[base + i];
    if (s >= 0 && leaf[base + i] != 0) atomicAdd(&sStart[s + 1], 1);
  }
  __syncthreads();
  if (w == 0) {
    int run = 0;
    for (int chunk = 0; chunk * 64 < n_species + 1; ++chunk) {
      int idx = chunk * 64 + lane;
      int v = (idx < n_species + 1) ? sStart[idx] : 0;
      for (int off = 1; off < 64; off <<= 1) {
        int t2 = __shfl_up(v, off);
        if (lane >= off) v += t2;
      }
      v += run;
      if (idx < n_species + 1) sStart[idx] = v;
      run = __shfl(v, 63);
    }
  }
  __syncthreads();
  for (int i = tid; i < npg; i += 768) {
    int s = sp[base + i];
    if (s >= 0 && leaf[base + i] != 0) {
      int pos = sStart[s] + atomicAdd(&sCnt[s], 1);
      sPar[pos] = i;
    }
  }
  __syncthreads();
  // means: thread per (species, dim-chunk); half8 row loads; frag-swizzled
  // bf16 scatter writes (s>=n_species slots stay zero from pre-zeroing).
  for (int idx = tid; idx < n_species * 8; idx += 768) {
    int s = idx >> 3, dc = idx & 7;
    int j0 = sStart[s], j1 = sStart[s + 1];
    float sum[8] = {0.f, 0.f, 0.f, 0.f, 0.f, 0.f, 0.f, 0.f};
    for (int j2 = j0; j2 < j1; ++j2) {
      int nd = sPar[j2];
      half8 v = *reinterpret_cast<const half8*>(
          &sA[nd * 64 + ((dc ^ (nd & 7)) << 3)]);
#pragma unroll
      for (int dd = 0; dd < 8; ++dd) sum[dd] += (float)v[dd];
    }
    float invc = (j1 > j0) ? 1.f / (float)(j1 - j0) : 0.f;
#pragma unroll
    for (int dd = 0; dd < 8; ++dd) {
      int d = dc * 8 + dd;
      int frag = (s >> 5) * 4 + (d >> 4);
      int ln = ((s >> 3) & 3) * 16 + (d & 15);
      sBfU[frag * 512 + ln * 8 + (s & 7)] = f2bf(sum[dd] * invc);
    }
  }
  if (tid < 7) {
    unsigned bits = 0;
    for (int b = 0; b < 32; ++b) {
      int s = tid * 32 + b;
      if (s < n_species && sStart[s + 1] > sStart[s]) bits |= 1u << b;
    }
    svb[tid] = bits;
  }
  __syncthreads();
  for (int e = tid; e < 400; e += 768) {
    unsigned ccv = 0;
#pragma unroll
    for (int w2 = 0; w2 < 7; ++w2) ccv += __popc(mfbits[e * 8 + w2] & svb[w2]);
    sInv[e] = 1.f / (float)max(ccv, 1u);
    sHas[e] = (ccv > 0) ? 1.f : 0.f;
  }
  __syncthreads();
  // ---- 4: clade-sum MFMA -> gmat (f16), has
  const bf16x8* A = reinterpret_cast<const bf16x8*>(mfA);
  const bf16x8* Bb = reinterpret_cast<const bf16x8*>(sBfU);
  for (int mt = w; mt < 25; mt += 12) {
    bf16x8 af[7];
#pragma unroll
    for (int kt = 0; kt < 7; ++kt) af[kt] = A[(mt * 7 + kt) * 64 + lane];
    f32x4 acc0 = {0.f, 0.f, 0.f, 0.f};
    f32x4 acc1 = {0.f, 0.f, 0.f, 0.f};
    f32x4 acc2 = {0.f, 0.f, 0.f, 0.f};
    f32x4 acc3 = {0.f, 0.f, 0.f, 0.f};
#pragma unroll
    for (int kt = 0; kt < 7; ++kt) {
      const bf16x8* B = Bb + kt * 256 + lane;
      acc0 = __builtin_amdgcn_mfma_f32_16x16x32_bf16(af[kt], B[0], acc0, 0, 0, 0);
      acc1 = __builtin_amdgcn_mfma_f32_16x16x32_bf16(af[kt], B[64], acc1, 0, 0, 0);
      acc2 = __builtin_amdgcn_mfma_f32_16x16x32_bf16(af[kt], B[128], acc2, 0, 0, 0);
      acc3 = __builtin_amdgcn_mfma_f32_16x16x32_bf16(af[kt], B[192], acc3, 0, 0, 0);
    }
    int rbase = mt * 16 + (lane >> 4) * 4;
    int col = lane & 15;
#pragma unroll
    for (int r = 0; r < 4; ++r) {
      int e = rbase + r;
      if (e >= n_edges) continue;
      float inv = sInv[e];
      _Float16* gp = gmat + ((size_t)e * n_gt + g) * 64 + col;
      gp[0] = (_Float16)(acc0[r] * inv);
      gp[16] = (_Float16)(acc1[r] * inv);
      gp[32] = (_Float16)(acc2[r] * inv);
      gp[48] = (_Float16)(acc3[r] * inv);
      if (col == 0) has[(size_t)e * n_gt + g] = sHas[e];
    }
  }
}

// Partial mean/std over a quarter of the gene trees per block.
__global__ __launch_bounds__(256) void k_stat2(const _Float16* __restrict__ gmat,
                                               const float* __restrict__ has,
                                               float* __restrict__ part,
                                               int n_gt) {
  __shared__ float red1[4][64];
  __shared__ float red2[4][64];
  __shared__ float redn[4];
  int b = blockIdx.x;
  int e = b >> 2, q = b & 3;
  int tid = threadIdx.x, w = tid >> 6, lane = tid & 63;
  const _Float16* ge = gmat + ((size_t)e * n_gt + q * 128) * 64;
  const float* he = has + (size_t)e * n_gt + q * 128;
  float S1 = 0.f, S2 = 0.f, nv = 0.f;
  for (int i = w; i < 128; i += 4) {
    float h = he[i];
    float v = (float)ge[i * 64 + lane];
    S1 += h * v;
    S2 += h * v * v;
    nv += h;
  }
  red1[w][lane] = S1;
  red2[w][lane] = S2;
  if (lane == 0) redn[w] = nv;
  __syncthreads();
  if (w == 0) {
    float s1 = 0.f, s2 = 0.f, n_v = 0.f;
#pragma unroll
    for (int j = 0; j < 4; ++j) {
      s1 += red1[j][lane];
      s2 += red2[j][lane];
      n_v += redn[j];
    }
    float* p = part + (size_t)b * 130;
    p[lane] = s1;
    p[64 + lane] = s2;
    if (lane == 0) p[128] = n_v;
  }
}

// Combine the 4 partials per edge and finalize mean/std.
__global__ __launch_bounds__(64) void k_fin(const float* __restrict__ part,
                                            float* __restrict__ out) {
  int e = blockIdx.x;
  int lane = threadIdx.x;
  float s1 = 0.f, s2 = 0.f, n_v = 0.f;
#pragma unroll
  for (int q = 0; q < 4; ++q) {
    const float* p = part + (size_t)(e * 4 + q) * 130;
    s1 += p[lane];
    s2 += p[64 + lane];
    n_v += p[128];
  }
  float mean = s1 / fmaxf(n_v, 1.f);
  float var = (s2 - s1 * s1 / fmaxf(n_v, 1.f)) / fmaxf(n_v - 1.f, 1.f);
  float stdv = (n_v > 1.f) ? sqrtf(fmaxf(var, 0.f)) : 0.f;
  out[(size_t)e * 128 + lane] = (n_v > 0.f) ? mean : 0.f;
  out[(size_t)e * 128 + 64 + lane] = stdv;
}

extern "C" void kernel_launch(void* const* d_in, const int* in_sizes, int n_in,
                              void* d_out, int out_size, void* d_ws, size_t ws_size,
                              hipStream_t stream) {
  (void)n_in; (void)out_size; (void)ws_size;
  const int* edge_index = (const int*)d_in[0];
  const int* sp_ids = (const int*)d_in[1];
  const int* leaf_mask = (const int*)d_in[2];
  const int* clade_mask = (const int*)d_in[4];
  const float* emb = (const float*)d_in[6];
  const float* W1 = (const float*)d_in[7];
  const float* b1 = (const float*)d_in[8];
  const float* W2 = (const float*)d_in[9];
  const float* b2 = (const float*)d_in[10];
  const float* eps = (const float*)d_in[11];
  const float* lng = (const float*)d_in[12];
  const float* lnb = (const float*)d_in[13];
  float* out = (float*)d_out;

  const int n_nodes = in_sizes[1];             // 204288
  const int nE = in_sizes[0] / 2;              // 407552 directed edges
  const int n_species = in_sizes[6] / 64 - 1;  // 200
  const int n_edges = in_sizes[4] / n_species; // 397
  const int n_gt = 512;                        // fixed problem size
  const int npg = n_nodes / n_gt;              // 399 nodes per gene tree

  const int* src = edge_index;       // first half: child ids
  const int* dst = edge_index + nE;  // first half: parent ids

  _Float16* gmat = (_Float16*)d_ws;
  size_t gsz =
      ((size_t)n_edges * n_gt * 64 * sizeof(_Float16) + 255ul) & ~255ul;
  float* has = (float*)((char*)d_ws + gsz);
  size_t hsz = ((size_t)n_edges * n_gt * sizeof(float) + 255ul) & ~255ul;
  unsigned short* mfA = (unsigned short*)((char*)d_ws + gsz + hsz);
  size_t masz = ((size_t)25 * 7 * 512 * sizeof(unsigned short) + 255ul) & ~255ul;
  unsigned* mfbits = (unsigned*)((char*)d_ws + gsz + hsz + masz);
  size_t mbsz = ((size_t)400 * 8 * sizeof(unsigned) + 255ul) & ~255ul;
  float* part = (float*)((char*)d_ws + gsz + hsz + masz + mbsz);

  k_prep<<<64, 256, 0, stream>>>(clade_mask, mfA, mfbits, n_edges, n_species);
  k_tree<<<n_gt, 768, 0, stream>>>(emb, sp_ids, leaf_mask, src, dst, W1, b1,
                                   W2, b2, eps, lng, lnb, mfA, mfbits, gmat,
                                   has, npg, n_species, n_edges, n_gt);
  k_stat2<<<n_edges * 4, 256, 0, stream>>>(gmat, has, part, n_gt);
  k_fin<<<n_edges, 64, 0, stream>>>(part, out);
}

// Round 15
// 116.947 us; speedup vs baseline: 1.1201x; 1.1201x over previous
//
#include <hip/hip_runtime.h>

// Fixed problem geometry: D=64, n_gt=512, npg=399 nodes/tree, 398 edges/tree.
#define SMAX 200
#define NPG 399

typedef __bf16 bf16x8 __attribute__((ext_vector_type(8)));
typedef _Float16 half8 __attribute__((ext_vector_type(8)));
typedef float f32x4 __attribute__((ext_vector_type(4)));

__device__ __forceinline__ unsigned short f2bf(float f) {
  unsigned u = __float_as_uint(f);
  unsigned r = (u + 0x7FFFu + ((u >> 16) & 1u)) >> 16;
  return (unsigned short)r;
}
// x rows live in LDS as 8 chunks of 8 f16; chunk slot = chunk ^ (node&7).
__device__ __forceinline__ int xel(int node, int dim) {
  return node * 64 + ((((dim >> 3)) ^ (node & 7)) << 3) + (dim & 7);
}

// Build A-operand fragments (mf as bf16, pre-swizzled into the 16x16x32 MFMA
// lane layout) and packed mf bitmasks.
__global__ __launch_bounds__(256) void k_prep(const int* __restrict__ clade,
                                              unsigned short* __restrict__ mfA,
                                              unsigned* __restrict__ mfbits,
                                              int n_edges, int n_species) {
  int stride = gridDim.x * 256;
  for (int idx = blockIdx.x * 256 + threadIdx.x; idx < 25 * 7 * 512;
       idx += stride) {
    int fi = idx >> 9, within = idx & 511;
    int mt = fi / 7, kt = fi % 7;
    int l = within >> 3, j = within & 7;
    int e = mt * 16 + (l & 15);
    int s = kt * 32 + ((l >> 4) & 3) * 8 + j;
    unsigned short v = 0;
    if (e < n_edges && s < n_species && clade[(size_t)e * n_species + s] != 0)
      v = 0x3F80;  // bf16(1.0)
    mfA[idx] = v;
  }
  for (int idx = blockIdx.x * 256 + threadIdx.x; idx < 400 * 8; idx += stride) {
    int e = idx >> 3, w = idx & 7;
    unsigned bits = 0;
    if (e < n_edges && w < 7) {
      for (int b = 0; b < 32; ++b) {
        int s = w * 32 + b;
        if (s < n_species && clade[(size_t)e * n_species + s] != 0)
          bits |= 1u << b;
      }
    }
    mfbits[idx] = bits;
  }
}

// Mega-kernel v6: one block per gene tree, 8 waves, weights resident both
// layers. Gather batches 4 children: 4 index loads in flight, then 8 row
// loads in flight, then accumulate — ~4x less serial LDS latency than the
// per-child chain.
__global__ __launch_bounds__(512) void k_tree(
    const float* __restrict__ emb, const int* __restrict__ sp,
    const int* __restrict__ leaf, const int* __restrict__ src,
    const int* __restrict__ dst, const float* __restrict__ W1,
    const float* __restrict__ b1, const float* __restrict__ W2,
    const float* __restrict__ b2, const float* __restrict__ eps_p,
    const float* __restrict__ gam, const float* __restrict__ bet,
    const unsigned short* __restrict__ mfA, const unsigned* __restrict__ mfbits,
    _Float16* __restrict__ gmat, float* __restrict__ has, int npg,
    int n_species, int n_edges, int n_gt) {
  __shared__ __attribute__((aligned(16))) _Float16 sA[NPG * 64];
  __shared__ __attribute__((aligned(16))) _Float16 sB[NPG * 64];
  __shared__ __attribute__((aligned(16))) _Float16 sWf[2][2][4096];
  __shared__ __attribute__((aligned(16))) _Float16 sT[8][1024];
  __shared__ int sStart[NPG + 1];
  __shared__ int sChild[NPG - 1];
  __shared__ int sPar[NPG];
  __shared__ int sCnt[NPG];

  int g = blockIdx.x, tid = threadIdx.x;
  int base = g * npg, nEt = npg - 1, ebase = g * nEt;
  int w = tid >> 6, lane = tid & 63;
  int cc = lane & 15, gq = lane >> 4;

  // ---- 0a: zero CSR counters
  for (int i = tid; i < npg + 1; i += 512) sStart[i] = 0;
  for (int i = tid; i < npg; i += 512) sCnt[i] = 0;
  __syncthreads();
  // ---- 0b: weights (both layers, frag-swizzled), emb gather (swizzled
  //          chunks), edges + histogram
  for (int idx = tid; idx < 4096; idx += 512) {
    int k = idx >> 6, n = idx & 63;
    int frag = (k >> 5) * 4 + (n >> 4);
    int ln = ((k >> 3) & 3) * 16 + (n & 15);
    int j = k & 7;
    int o = frag * 512 + ln * 8 + j;
    sWf[0][0][o] = (_Float16)W1[idx];
    sWf[0][1][o] = (_Float16)W2[idx];
    sWf[1][0][o] = (_Float16)W1[4096 + idx];
    sWf[1][1][o] = (_Float16)W2[4096 + idx];
  }
  for (int idx = tid; idx < npg * 8; idx += 512) {
    int node = idx >> 3, ch = idx & 7;
    int s = sp[base + node];
    int row = (s < 0) ? n_species : s;
    float4 v0 = reinterpret_cast<const float4*>(emb)[row * 16 + ch * 2];
    float4 v1 = reinterpret_cast<const float4*>(emb)[row * 16 + ch * 2 + 1];
    half8 h;
    h[0] = (_Float16)v0.x; h[1] = (_Float16)v0.y;
    h[2] = (_Float16)v0.z; h[3] = (_Float16)v0.w;
    h[4] = (_Float16)v1.x; h[5] = (_Float16)v1.y;
    h[6] = (_Float16)v1.z; h[7] = (_Float16)v1.w;
    *reinterpret_cast<half8*>(&sA[node * 64 + ((ch ^ (node & 7)) << 3)]) = h;
  }
  for (int i = tid; i < nEt; i += 512) {
    int c = src[ebase + i] - base;
    int p = dst[ebase + i] - base;
    sPar[c] = p;
    atomicAdd(&sStart[p + 1], 1);
  }
  __syncthreads();
  // ---- 0c: inclusive scan (wave 0, shfl)
  if (w == 0) {
    int run = 0;
    for (int chunk = 0; chunk * 64 < npg + 1; ++chunk) {
      int idx = chunk * 64 + lane;
      int v = (idx < npg + 1) ? sStart[idx] : 0;
      for (int off = 1; off < 64; off <<= 1) {
        int t2 = __shfl_up(v, off);
        if (lane >= off) v += t2;
      }
      v += run;
      if (idx < npg + 1) sStart[idx] = v;
      run = __shfl(v, 63);
    }
  }
  __syncthreads();
  // ---- 0d: scatter children
  for (int c = tid + 1; c < npg; c += 512) {
    int p = sPar[c];
    int pos = sStart[p] + atomicAdd(&sCnt[p], 1);
    sChild[pos] = c;
  }
  __syncthreads();

  // ---- layers
  _Float16* tb = sT[w];
  int t0w = w * 3;
  int t1w = (w == 7) ? 25 : t0w + 3;
  for (int l = 0; l < 2; ++l) {
    const _Float16* xin = l ? sB : sA;
    _Float16* xout = l ? sA : sB;
    const half8* xin8 = reinterpret_cast<const half8*>(xin);
    float e1 = 1.0f + eps_p[l];
    float b1v[4], b2v[4], gv[4], bv[4];
#pragma unroll
    for (int nt = 0; nt < 4; ++nt) {
      b1v[nt] = b1[l * 64 + cc + 16 * nt];
      b2v[nt] = b2[l * 64 + cc + 16 * nt];
      gv[nt] = gam[l * 64 + cc + 16 * nt];
      bv[nt] = bet[l * 64 + cc + 16 * nt];
    }
    const half8* B1 = reinterpret_cast<const half8*>(sWf[l][0]);
    const half8* B2 = reinterpret_cast<const half8*>(sWf[l][1]);
    for (int t = t0w; t < t1w; ++t) {
      int n0 = t * 16;
      // lane-parallel msg gather; accumulator IS the A-fragment (f32)
      int node = n0 + cc;
      bool vn = node < npg;
      int nd2 = vn ? node : 0;
      int j0v = vn ? sStart[nd2] : 0;
      int cnt = vn ? (sStart[nd2 + 1] - j0v) : 0;
      half8 s0 = xin8[nd2 * 8 + (gq ^ (nd2 & 7))];
      half8 s1 = xin8[nd2 * 8 + ((4 + gq) ^ (nd2 & 7))];
      bool hasp = vn && node > 0;
      int pr = hasp ? sPar[nd2] : 0;
      half8 p0 = xin8[pr * 8 + (gq ^ (pr & 7))];
      half8 p1 = xin8[pr * 8 + ((4 + gq) ^ (pr & 7))];
      float a0f[8], a1f[8];
#pragma unroll
      for (int d = 0; d < 8; ++d) {
        a0f[d] = e1 * (float)s0[d] + (hasp ? (float)p0[d] : 0.f);
        a1f[d] = e1 * (float)s1[d] + (hasp ? (float)p1[d] : 0.f);
      }
      int cmax = cnt;
#pragma unroll
      for (int off = 1; off < 64; off <<= 1)
        cmax = max(cmax, __shfl_xor(cmax, off));
      cmax = __builtin_amdgcn_readfirstlane(cmax);
      // batched-4 gather: 4 index loads in flight, then 8 row loads in
      // flight, then accumulate.
      for (int k0 = 0; k0 < cmax; k0 += 4) {
        int ci[4];
#pragma unroll
        for (int jj = 0; jj < 4; ++jj) {
          int kk = k0 + jj;
          ci[jj] = sChild[(kk < cnt) ? (j0v + kk) : 0];
        }
        half8 v0[4], v1[4];
#pragma unroll
        for (int jj = 0; jj < 4; ++jj) {
          int c = ci[jj];
          v0[jj] = xin8[c * 8 + (gq ^ (c & 7))];
          v1[jj] = xin8[c * 8 + ((4 + gq) ^ (c & 7))];
        }
#pragma unroll
        for (int jj = 0; jj < 4; ++jj) {
          if (k0 + jj < cnt) {
#pragma unroll
            for (int d = 0; d < 8; ++d) {
              a0f[d] += (float)v0[jj][d];
              a1f[d] += (float)v1[jj][d];
            }
          }
        }
      }
      half8 a0, a1;
#pragma unroll
      for (int d = 0; d < 8; ++d) {
        a0[d] = (_Float16)a0f[d];
        a1[d] = (_Float16)a1f[d];
      }
      // MFMA 1 + relu -> per-wave tile buffer (XOR-swizzled)
      f32x4 tacc[4];
#pragma unroll
      for (int nt = 0; nt < 4; ++nt) tacc[nt] = (f32x4){0.f, 0.f, 0.f, 0.f};
#pragma unroll
      for (int nt = 0; nt < 4; ++nt) {
        tacc[nt] = __builtin_amdgcn_mfma_f32_16x16x32_f16(
            a0, B1[nt * 64 + lane], tacc[nt], 0, 0, 0);
        tacc[nt] = __builtin_amdgcn_mfma_f32_16x16x32_f16(
            a1, B1[(4 + nt) * 64 + lane], tacc[nt], 0, 0, 0);
      }
#pragma unroll
      for (int nt = 0; nt < 4; ++nt)
#pragma unroll
        for (int r = 0; r < 4; ++r) {
          int m = gq * 4 + r;
          tb[m * 64 + ((cc + 16 * nt) ^ ((m & 7) << 3))] =
              (_Float16)fmaxf(tacc[nt][r] + b1v[nt], 0.f);
        }
      int sw = (cc & 7) << 3;
      half8 c0 =
          *reinterpret_cast<const half8*>(&tb[cc * 64 + ((gq * 8) ^ sw)]);
      half8 c1 =
          *reinterpret_cast<const half8*>(&tb[cc * 64 + ((32 + gq * 8) ^ sw)]);
      f32x4 hacc[4];
#pragma unroll
      for (int nt = 0; nt < 4; ++nt) hacc[nt] = (f32x4){0.f, 0.f, 0.f, 0.f};
#pragma unroll
      for (int nt = 0; nt < 4; ++nt) {
        hacc[nt] = __builtin_amdgcn_mfma_f32_16x16x32_f16(
            c0, B2[nt * 64 + lane], hacc[nt], 0, 0, 0);
        hacc[nt] = __builtin_amdgcn_mfma_f32_16x16x32_f16(
            c1, B2[(4 + nt) * 64 + lane], hacc[nt], 0, 0, 0);
      }
      // residual + LayerNorm (f32)
      float y[4][4];
#pragma unroll
      for (int r = 0; r < 4; ++r) {
        int nd3 = n0 + gq * 4 + r;
        bool v3 = nd3 < npg;
        int nds = v3 ? nd3 : 0;
#pragma unroll
        for (int nt = 0; nt < 4; ++nt) {
          float xv = (float)xin[xel(nds, cc + 16 * nt)];
          y[r][nt] = (v3 ? xv : 0.f) + hacc[nt][r] + b2v[nt];
        }
      }
#pragma unroll
      for (int r = 0; r < 4; ++r) {
        float s = y[r][0] + y[r][1] + y[r][2] + y[r][3];
        s += __shfl_xor(s, 1);
        s += __shfl_xor(s, 2);
        s += __shfl_xor(s, 4);
        s += __shfl_xor(s, 8);
        float mu = s * (1.f / 64.f);
        float d0 = y[r][0] - mu, d1 = y[r][1] - mu;
        float d2 = y[r][2] - mu, d3 = y[r][3] - mu;
        float v = d0 * d0 + d1 * d1 + d2 * d2 + d3 * d3;
        v += __shfl_xor(v, 1);
        v += __shfl_xor(v, 2);
        v += __shfl_xor(v, 4);
        v += __shfl_xor(v, 8);
        float iv = rsqrtf(v * (1.f / 64.f) + 1e-5f);
        int nd3 = n0 + gq * 4 + r;
        if (nd3 < npg) {
#pragma unroll
          for (int nt = 0; nt < 4; ++nt)
            xout[xel(nd3, cc + 16 * nt)] =
                (_Float16)((y[r][nt] - mu) * iv * gv[nt] + bv[nt]);
        }
      }
    }
    __syncthreads();
  }

  // ---- 3: species pooling (final x is in sA). Aliases: sBf on dead sWf,
  //         aux on dead sT.
  unsigned short* sBfU = reinterpret_cast<unsigned short*>(&sWf[0][0][0]);
  char* aux = reinterpret_cast<char*>(&sT[0][0]);
  float* sInv = reinterpret_cast<float*>(aux);
  float* sHas = reinterpret_cast<float*>(aux + 1600);
  unsigned* svb = reinterpret_cast<unsigned*>(aux + 3200);
  for (int i = tid; i < n_species + 1; i += 512) sStart[i] = 0;
  for (int i = tid; i < n_species; i += 512) sCnt[i] = 0;
  {
    float4 z4 = {0.f, 0.f, 0.f, 0.f};
    for (int i = tid; i < 1792; i += 512)
      reinterpret_cast<float4*>(sBfU)[i] = z4;
  }
  __syncthreads();
  for (int i = tid; i < npg; i += 512) {
    int s = sp[base + i];
    if (s >= 0 && leaf[base + i] != 0) atomicAdd(&sStart[s + 1], 1);
  }
  __syncthreads();
  if (w == 0) {
    int run = 0;
    for (int chunk = 0; chunk * 64 < n_species + 1; ++chunk) {
      int idx = chunk * 64 + lane;
      int v = (idx < n_species + 1) ? sStart[idx] : 0;
      for (int off = 1; off < 64; off <<= 1) {
        int t2 = __shfl_up(v, off);
        if (lane >= off) v += t2;
      }
      v += run;
      if (idx < n_species + 1) sStart[idx] = v;
      run = __shfl(v, 63);
    }
  }
  __syncthreads();
  for (int i = tid; i < npg; i += 512) {
    int s = sp[base + i];
    if (s >= 0 && leaf[base + i] != 0) {
      int pos = sStart[s] + atomicAdd(&sCnt[s], 1);
      sPar[pos] = i;
    }
  }
  __syncthreads();
  // means: thread per (species, dim-chunk); half8 row loads; frag-swizzled
  // bf16 scatter writes (s>=n_species slots stay zero from pre-zeroing).
  for (int idx = tid; idx < n_species * 8; idx += 512) {
    int s = idx >> 3, dc = idx & 7;
    int j0 = sStart[s], j1 = sStart[s + 1];
    float sum[8] = {0.f, 0.f, 0.f, 0.f, 0.f, 0.f, 0.f, 0.f};
    for (int j2 = j0; j2 < j1; ++j2) {
      int nd = sPar[j2];
      half8 v = *reinterpret_cast<const half8*>(
          &sA[nd * 64 + ((dc ^ (nd & 7)) << 3)]);
#pragma unroll
      for (int dd = 0; dd < 8; ++dd) sum[dd] += (float)v[dd];
    }
    float invc = (j1 > j0) ? 1.f / (float)(j1 - j0) : 0.f;
#pragma unroll
    for (int dd = 0; dd < 8; ++dd) {
      int d = dc * 8 + dd;
      int frag = (s >> 5) * 4 + (d >> 4);
      int ln = ((s >> 3) & 3) * 16 + (d & 15);
      sBfU[frag * 512 + ln * 8 + (s & 7)] = f2bf(sum[dd] * invc);
    }
  }
  if (tid < 7) {
    unsigned bits = 0;
    for (int b = 0; b < 32; ++b) {
      int s = tid * 32 + b;
      if (s < n_species && sStart[s + 1] > sStart[s]) bits |= 1u << b;
    }
    svb[tid] = bits;
  }
  __syncthreads();
  for (int e = tid; e < 400; e += 512) {
    unsigned ccv = 0;
#pragma unroll
    for (int w2 = 0; w2 < 7; ++w2) ccv += __popc(mfbits[e * 8 + w2] & svb[w2]);
    sInv[e] = 1.f / (float)max(ccv, 1u);
    sHas[e] = (ccv > 0) ? 1.f : 0.f;
  }
  __syncthreads();
  // ---- 4: clade-sum MFMA -> gmat (f16), has
  const bf16x8* A = reinterpret_cast<const bf16x8*>(mfA);
  const bf16x8* Bb = reinterpret_cast<const bf16x8*>(sBfU);
  for (int mt = w; mt < 25; mt += 8) {
    bf16x8 af[7];
#pragma unroll
    for (int kt = 0; kt < 7; ++kt) af[kt] = A[(mt * 7 + kt) * 64 + lane];
    f32x4 acc0 = {0.f, 0.f, 0.f, 0.f};
    f32x4 acc1 = {0.f, 0.f, 0.f, 0.f};
    f32x4 acc2 = {0.f, 0.f, 0.f, 0.f};
    f32x4 acc3 = {0.f, 0.f, 0.f, 0.f};
#pragma unroll
    for (int kt = 0; kt < 7; ++kt) {
      const bf16x8* B = Bb + kt * 256 + lane;
      acc0 = __builtin_amdgcn_mfma_f32_16x16x32_bf16(af[kt], B[0], acc0, 0, 0, 0);
      acc1 = __builtin_amdgcn_mfma_f32_16x16x32_bf16(af[kt], B[64], acc1, 0, 0, 0);
      acc2 = __builtin_amdgcn_mfma_f32_16x16x32_bf16(af[kt], B[128], acc2, 0, 0, 0);
      acc3 = __builtin_amdgcn_mfma_f32_16x16x32_bf16(af[kt], B[192], acc3, 0, 0, 0);
    }
    int rbase = mt * 16 + (lane >> 4) * 4;
    int col = lane & 15;
#pragma unroll
    for (int r = 0; r < 4; ++r) {
      int e = rbase + r;
      if (e >= n_edges) continue;
      float inv = sInv[e];
      _Float16* gp = gmat + ((size_t)e * n_gt + g) * 64 + col;
      gp[0] = (_Float16)(acc0[r] * inv);
      gp[16] = (_Float16)(acc1[r] * inv);
      gp[32] = (_Float16)(acc2[r] * inv);
      gp[48] = (_Float16)(acc3[r] * inv);
      if (col == 0) has[(size_t)e * n_gt + g] = sHas[e];
    }
  }
}

// Partial mean/std over a quarter of the gene trees per block.
__global__ __launch_bounds__(256) void k_stat2(const _Float16* __restrict__ gmat,
                                               const float* __restrict__ has,
                                               float* __restrict__ part,
                                               int n_gt) {
  __shared__ float red1[4][64];
  __shared__ float red2[4][64];
  __shared__ float redn[4];
  int b = blockIdx.x;
  int e = b >> 2, q = b & 3;
  int tid = threadIdx.x, w = tid >> 6, lane = tid & 63;
  const _Float16* ge = gmat + ((size_t)e * n_gt + q * 128) * 64;
  const float* he = has + (size_t)e * n_gt + q * 128;
  float S1 = 0.f, S2 = 0.f, nv = 0.f;
  for (int i = w; i < 128; i += 4) {
    float h = he[i];
    float v = (float)ge[i * 64 + lane];
    S1 += h * v;
    S2 += h * v * v;
    nv += h;
  }
  red1[w][lane] = S1;
  red2[w][lane] = S2;
  if (lane == 0) redn[w] = nv;
  __syncthreads();
  if (w == 0) {
    float s1 = 0.f, s2 = 0.f, n_v = 0.f;
#pragma unroll
    for (int j = 0; j < 4; ++j) {
      s1 += red1[j][lane];
      s2 += red2[j][lane];
      n_v += redn[j];
    }
    float* p = part + (size_t)b * 130;
    p[lane] = s1;
    p[64 + lane] = s2;
    if (lane == 0) p[128] = n_v;
  }
}

// Combine the 4 partials per edge and finalize mean/std.
__global__ __launch_bounds__(64) void k_fin(const float* __restrict__ part,
                                            float* __restrict__ out) {
  int e = blockIdx.x;
  int lane = threadIdx.x;
  float s1 = 0.f, s2 = 0.f, n_v = 0.f;
#pragma unroll
  for (int q = 0; q < 4; ++q) {
    const float* p = part + (size_t)(e * 4 + q) * 130;
    s1 += p[lane];
    s2 += p[64 + lane];
    n_v += p[128];
  }
  float mean = s1 / fmaxf(n_v, 1.f);
  float var = (s2 - s1 * s1 / fmaxf(n_v, 1.f)) / fmaxf(n_v - 1.f, 1.f);
  float stdv = (n_v > 1.f) ? sqrtf(fmaxf(var, 0.f)) : 0.f;
  out[(size_t)e * 128 + lane] = (n_v > 0.f) ? mean : 0.f;
  out[(size_t)e * 128 + 64 + lane] = stdv;
}

extern "C" void kernel_launch(void* const* d_in, const int* in_sizes, int n_in,
                              void* d_out, int out_size, void* d_ws, size_t ws_size,
                              hipStream_t stream) {
  (void)n_in; (void)out_size; (void)ws_size;
  const int* edge_index = (const int*)d_in[0];
  const int* sp_ids = (const int*)d_in[1];
  const int* leaf_mask = (const int*)d_in[2];
  const int* clade_mask = (const int*)d_in[4];
  const float* emb = (const float*)d_in[6];
  const float* W1 = (const float*)d_in[7];
  const float* b1 = (const float*)d_in[8];
  const float* W2 = (const float*)d_in[9];
  const float* b2 = (const float*)d_in[10];
  const float* eps = (const float*)d_in[11];
  const float* lng = (const float*)d_in[12];
  const float* lnb = (const float*)d_in[13];
  float* out = (float*)d_out;

  const int n_nodes = in_sizes[1];             // 204288
  const int nE = in_sizes[0] / 2;              // 407552 directed edges
  const int n_species = in_sizes[6] / 64 - 1;  // 200
  const int n_edges = in_sizes[4] / n_species; // 397
  const int n_gt = 512;                        // fixed problem size
  const int npg = n_nodes / n_gt;              // 399 nodes per gene tree

  const int* src = edge_index;       // first half: child ids
  const int* dst = edge_index + nE;  // first half: parent ids

  _Float16* gmat = (_Float16*)d_ws;
  size_t gsz =
      ((size_t)n_edges * n_gt * 64 * sizeof(_Float16) + 255ul) & ~255ul;
  float* has = (float*)((char*)d_ws + gsz);
  size_t hsz = ((size_t)n_edges * n_gt * sizeof(float) + 255ul) & ~255ul;
  unsigned short* mfA = (unsigned short*)((char*)d_ws + gsz + hsz);
  size_t masz = ((size_t)25 * 7 * 512 * sizeof(unsigned short) + 255ul) & ~255ul;
  unsigned* mfbits = (unsigned*)((char*)d_ws + gsz + hsz + masz);
  size_t mbsz = ((size_t)400 * 8 * sizeof(unsigned) + 255ul) & ~255ul;
  float* part = (float*)((char*)d_ws + gsz + hsz + masz + mbsz);

  k_prep<<<64, 256, 0, stream>>>(clade_mask, mfA, mfbits, n_edges, n_species);
  k_tree<<<n_gt, 512, 0, stream>>>(emb, sp_ids, leaf_mask, src, dst, W1, b1,
                                   W2, b2, eps, lng, lnb, mfA, mfbits, gmat,
                                   has, npg, n_species, n_edges, n_gt);
  k_stat2<<<n_edges * 4, 256, 0, stream>>>(gmat, has, part, n_gt);
  k_fin<<<n_edges, 64, 0, stream>>>(part, out);
}